// Round 1
// 557.669 us; speedup vs baseline: 1.2829x; 1.2829x over previous
//
#include <hip/hip_runtime.h>

#define HIDDEN 5120
#define NEXP 160
#define NGRP 8
#define GSIZE 20
#define TOPKG 3
#define TOPK 6

#define BT 128                 // tokens per gemm block
#define KC 64                  // k per LDS stage
#define NSTEP (HIDDEN / 32)    // 160 k-steps total
#define BPL (NSTEP * 10 * 64)  // f16x8 units per packed-W plane

typedef _Float16 f16;
typedef _Float16 f16x4 __attribute__((ext_vector_type(4)));
typedef _Float16 f16x8 __attribute__((ext_vector_type(8)));
typedef float f32x4 __attribute__((ext_vector_type(4)));

// ---------- K0: pack W [160][5120] fp32 -> f16 hi/lo planes in MFMA B-frag order ----
// plane element (k-step s, n-frag f, lane l, slot j) = w[f*16+(l&15)][s*32+(l>>4)*8+j]
// lo plane holds (w - f16(w)) * 4096 so it stays in f16 normal range.
__global__ __launch_bounds__(256) void pack_w(const float* __restrict__ w,
                                              f16* __restrict__ bpk) {
    int idx = blockIdx.x * 256 + threadIdx.x;
    if (idx >= NSTEP * 10 * 64) return;
    int l = idx & 63;
    int rest = idx >> 6;
    int f = rest % 10;
    int s = rest / 10;
    int n = f * 16 + (l & 15);
    int k0 = s * 32 + (l >> 4) * 8;
    const float* src = w + (size_t)n * HIDDEN + k0;
    f16x8 hi, lo;
#pragma unroll
    for (int j = 0; j < 8; ++j) {
        float v = src[j];
        f16 hv = (f16)v;
        hi[j] = hv;
        lo[j] = (f16)((v - (float)hv) * 4096.0f);
    }
    f16x8* dst = (f16x8*)bpk;
    dst[idx] = hi;
    dst[BPL + idx] = lo;
}

// ---------- K1: split-f16 MFMA GEMM, logits partials [KSP][T][160] f32 ----------
// 8 waves = 4 token-groups x 2 expert-halves. Per wave: 32 tokens (2 M-frags) x 80
// experts (5 N-frags). x fp32 -> hi/lo f16 staged in XOR-swizzled double-buffered LDS.
// B frags read directly from global (L1/L2-resident, 3.3 MB).
template <int KSP>
__global__ __launch_bounds__(512, 2) void gemm_mfma(const float* __restrict__ x,
                                                    const f16* __restrict__ bpk,
                                                    float* __restrict__ part, int T) {
    constexpr int KPB = HIDDEN / KSP;  // k per block
    constexpr int NCH = KPB / KC;      // LDS chunks per block
    __shared__ __align__(16) f16 Ah[2][BT * KC];
    __shared__ __align__(16) f16 Al[2][BT * KC];

    const int tid  = threadIdx.x;
    const int lane = tid & 63;
    const int wv   = tid >> 6;
    const int bx   = blockIdx.x;
    const int tile = bx / KSP;
    const int ks   = bx - tile * KSP;
    const int t0   = tile * BT;
    const int tg   = wv >> 1;  // token group (32 tokens)
    const int eh   = wv & 1;   // expert half (80 experts)

    // staging map: thread = (trow, q); covers tokens trow+32r, k-quad q
    const int q    = tid & 15;
    const int trow = tid >> 4;
    const float* xbase = x + (size_t)t0 * HIDDEN + ks * KPB + q * 4;

    float4 xc[4];
#pragma unroll
    for (int r = 0; r < 4; ++r)
        xc[r] = *(const float4*)(xbase + (size_t)(trow + 32 * r) * HIDDEN);

    f32x4 acc0[2][5], acc1[2][5];
    const f32x4 z4 = {0.f, 0.f, 0.f, 0.f};
#pragma unroll
    for (int a = 0; a < 2; ++a)
#pragma unroll
        for (int b = 0; b < 5; ++b) { acc0[a][b] = z4; acc1[a][b] = z4; }

    // stage chunk 0 -> buf 0 (XOR swizzle on 8B granules keeps b128 reads conflict-free)
#pragma unroll
    for (int r = 0; r < 4; ++r) {
        int tt = trow + 32 * r;
        float vv[4] = {xc[r].x, xc[r].y, xc[r].z, xc[r].w};
        f16x4 hi, lo;
#pragma unroll
        for (int j = 0; j < 4; ++j) {
            f16 hv = (f16)vv[j];
            hi[j] = hv;
            lo[j] = (f16)((vv[j] - (float)hv) * 4096.0f);
        }
        int ix = tt * KC + ((q * 4) ^ ((tt & 7) * 8));
        *(f16x4*)&Ah[0][ix] = hi;
        *(f16x4*)&Al[0][ix] = lo;
    }
    __syncthreads();

    const f16x8* Bh = (const f16x8*)bpk;
    const int m16 = lane & 15;
    const int h4  = lane >> 4;

    int buf = 0;
    for (int c = 0; c < NCH; ++c) {
        // prefetch next chunk (clamped; last-iter redundancy is harmless)
        int cn = (c + 1 < NCH) ? c + 1 : c;
        float4 xn[4];
#pragma unroll
        for (int r = 0; r < 4; ++r)
            xn[r] = *(const float4*)(xbase + (size_t)(trow + 32 * r) * HIDDEN + cn * KC);

#pragma unroll
        for (int s = 0; s < 2; ++s) {
            const int koff = s * 32 + h4 * 8;
            const int tt0 = tg * 32 + m16;
            const int tt1 = tt0 + 16;
            const int i0 = tt0 * KC + (koff ^ ((tt0 & 7) * 8));
            const int i1 = tt1 * KC + (koff ^ ((tt1 & 7) * 8));
            f16x8 ah0 = *(const f16x8*)&Ah[buf][i0];
            f16x8 ah1 = *(const f16x8*)&Ah[buf][i1];
            f16x8 al0 = *(const f16x8*)&Al[buf][i0];
            f16x8 al1 = *(const f16x8*)&Al[buf][i1];
            const int sg = ks * (NCH * 2) + c * 2 + s;
            const f16x8* bh = Bh + ((size_t)sg * 10 + eh * 5) * 64 + lane;
#pragma unroll
            for (int nf = 0; nf < 5; ++nf) {
                f16x8 vbh = bh[nf * 64];
                f16x8 vbl = bh[BPL + nf * 64];
                acc0[0][nf] = __builtin_amdgcn_mfma_f32_16x16x32_f16(ah0, vbh, acc0[0][nf], 0, 0, 0);
                acc0[1][nf] = __builtin_amdgcn_mfma_f32_16x16x32_f16(ah1, vbh, acc0[1][nf], 0, 0, 0);
                acc1[0][nf] = __builtin_amdgcn_mfma_f32_16x16x32_f16(ah0, vbl, acc1[0][nf], 0, 0, 0);
                acc1[1][nf] = __builtin_amdgcn_mfma_f32_16x16x32_f16(ah1, vbl, acc1[1][nf], 0, 0, 0);
                acc1[0][nf] = __builtin_amdgcn_mfma_f32_16x16x32_f16(al0, vbh, acc1[0][nf], 0, 0, 0);
                acc1[1][nf] = __builtin_amdgcn_mfma_f32_16x16x32_f16(al1, vbh, acc1[1][nf], 0, 0, 0);
            }
        }

        // stage next chunk into the other buffer (no conflict with in-flight reads)
#pragma unroll
        for (int r = 0; r < 4; ++r) {
            int tt = trow + 32 * r;
            float vv[4] = {xn[r].x, xn[r].y, xn[r].z, xn[r].w};
            f16x4 hi, lo;
#pragma unroll
            for (int j = 0; j < 4; ++j) {
                f16 hv = (f16)vv[j];
                hi[j] = hv;
                lo[j] = (f16)((vv[j] - (float)hv) * 4096.0f);
            }
            int ix = tt * KC + ((q * 4) ^ ((tt & 7) * 8));
            *(f16x4*)&Ah[buf ^ 1][ix] = hi;
            *(f16x4*)&Al[buf ^ 1][ix] = lo;
        }
        __syncthreads();
        buf ^= 1;
    }

    // epilogue: logit = acc0 + acc1/4096; C/D map: col=lane&15 (expert), row=h4*4+r (token)
    const float s12 = 1.0f / 4096.0f;
#pragma unroll
    for (int mf = 0; mf < 2; ++mf) {
#pragma unroll
        for (int nf = 0; nf < 5; ++nf) {
            int e  = eh * 80 + nf * 16 + m16;
            int tb = t0 + tg * 32 + mf * 16 + h4 * 4;
#pragma unroll
            for (int r = 0; r < 4; ++r) {
                float v = acc0[mf][nf][r] + acc1[mf][nf][r] * s12;
                part[((size_t)ks * T + (tb + r)) * NEXP + e] = v;
            }
        }
    }
}

// ---------- K2: one thread per token: combine partials + grouped top-k ----------
template <int KSP>
__global__ __launch_bounds__(64) void moe_topk2(const float* __restrict__ part,
                                                float* __restrict__ out, int T) {
    int t = blockIdx.x * 64 + threadIdx.x;
    if (t >= T) return;
    const float4* b0 = (const float4*)(part + (size_t)t * NEXP);
    const size_t ps = (size_t)T * (NEXP / 4);

    float4 row[40];
    float gmax[NGRP];
#pragma unroll
    for (int g = 0; g < NGRP; ++g) {
        float m = -3e38f;
#pragma unroll
        for (int j = 0; j < 5; ++j) {
            float4 v = b0[g * 5 + j];
#pragma unroll
            for (int p = 1; p < KSP; ++p) {
                float4 a = b0[(size_t)p * ps + g * 5 + j];
                v.x += a.x; v.y += a.y; v.z += a.z; v.w += a.w;
            }
            row[g * 5 + j] = v;
            m = fmaxf(m, fmaxf(fmaxf(v.x, v.y), fmaxf(v.z, v.w)));
        }
        gmax[g] = m;
    }

    // top-3 groups, lowest index wins ties (matches lax.top_k)
    unsigned gmask = 0;
#pragma unroll
    for (int r = 0; r < TOPKG; ++r) {
        float bv = -3e38f; int bi = 0;
#pragma unroll
        for (int g = 0; g < NGRP; ++g) {
            bool elig = !((gmask >> g) & 1);
            if (elig && gmax[g] > bv) { bv = gmax[g]; bi = g; }
        }
        gmask |= 1u << bi;
    }

    // stable top-6 insertion over selected groups (ascending e, strict >)
    float lv[TOPK]; int li[TOPK];
#pragma unroll
    for (int r = 0; r < TOPK; ++r) { lv[r] = -3e38f; li[r] = 1 << 20; }
#pragma unroll
    for (int g = 0; g < NGRP; ++g) {
        bool sel = (gmask >> g) & 1;
#pragma unroll
        for (int j = 0; j < 5; ++j) {
            float4 v = row[g * 5 + j];
            float vv[4] = {v.x, v.y, v.z, v.w};
#pragma unroll
            for (int cc = 0; cc < 4; ++cc) {
                float sv = sel ? vv[cc] : -3e38f;
                int e = g * GSIZE + j * 4 + cc;
                if (sv > lv[TOPK - 1]) {
                    lv[TOPK - 1] = sv; li[TOPK - 1] = e;
#pragma unroll
                    for (int qq = TOPK - 1; qq > 0; --qq) {
                        if (lv[qq] > lv[qq - 1]) {
                            float tv = lv[qq]; lv[qq] = lv[qq - 1]; lv[qq - 1] = tv;
                            int ti = li[qq]; li[qq] = li[qq - 1]; li[qq - 1] = ti;
                        }
                    }
                }
            }
        }
    }

    float m0 = lv[0];
    float ssum = 0.f, w6[TOPK];
#pragma unroll
    for (int r = 0; r < TOPK; ++r) { w6[r] = expf(lv[r] - m0); ssum += w6[r]; }
    float inv = 1.f / (ssum + 1e-20f);
#pragma unroll
    for (int r = 0; r < TOPK; ++r) {
        out[(size_t)t * TOPK + r] = (float)li[r];
        out[(size_t)T * TOPK + (size_t)t * TOPK + r] = w6[r] * inv;
    }
}

extern "C" void kernel_launch(void* const* d_in, const int* in_sizes, int n_in,
                              void* d_out, int out_size, void* d_ws, size_t ws_size,
                              hipStream_t stream) {
    const float* x = (const float*)d_in[0];
    const float* w = (const float*)d_in[1];
    float* out = (float*)d_out;
    const int T = in_sizes[0] / HIDDEN;  // 16384

    f16* bpk    = (f16*)d_ws;                                             // 3.28 MB
    float* part = (float*)((char*)d_ws + (size_t)HIDDEN * NEXP * sizeof(float));

    pack_w<<<(NSTEP * 10 * 64 + 255) / 256, 256, 0, stream>>>(w, bpk);

    size_t need4 = ((size_t)HIDDEN * NEXP + (size_t)4 * T * NEXP) * sizeof(float);
    if (ws_size >= need4) {
        gemm_mfma<4><<<(T / BT) * 4, 512, 0, stream>>>(x, bpk, part, T);
        moe_topk2<4><<<(T + 63) / 64, 64, 0, stream>>>(part, out, T);
    } else {
        gemm_mfma<2><<<(T / BT) * 2, 512, 0, stream>>>(x, bpk, part, T);
        moe_topk2<2><<<(T + 63) / 64, 64, 0, stream>>>(part, out, T);
    }
}

// Round 2
// 498.005 us; speedup vs baseline: 1.4366x; 1.1198x over previous
//
#include <hip/hip_runtime.h>

#define HIDDEN 5120
#define NEXP 160
#define NGRP 8
#define GSIZE 20
#define TOPKG 3
#define TOPK 6

#define KSP 2                    // K-split (partial planes)
#define BT 64                    // tokens per gemm block
#define KC 32                    // k per chunk (= one MFMA k-step)
#define NSTEP (HIDDEN / 32)      // 160 global k-steps
#define BPL (NSTEP * 10 * 64)    // f16x8 units per packed-W plane
#define KPB (HIDDEN / KSP)       // 2560 k per block
#define NCH (KPB / KC)           // 80 chunks
#define F16_MIN_NORM 6.104e-5f   // denorm guard: MFMA may flush f16 denorms

typedef _Float16 f16;
typedef _Float16 f16x4 __attribute__((ext_vector_type(4)));
typedef _Float16 f16x8 __attribute__((ext_vector_type(8)));
typedef float f32x4 __attribute__((ext_vector_type(4)));

__device__ __forceinline__ void gl_lds16(const void* g, void* l) {
    __builtin_amdgcn_global_load_lds((const __attribute__((address_space(1))) void*)g,
                                     (__attribute__((address_space(3))) void*)l, 16, 0, 0);
}

// ---------- K0: pack W fp32 -> f16 hi/lo planes in MFMA B-frag order ----------
// plane element (k-step s, n-frag f, lane l, slot j) = w[f*16+(l&15)][s*32+(l>>4)*8+j]
// lo plane = (w - f16(w)) * 4096. |w|<f16_min_normal goes entirely to lo.
__global__ __launch_bounds__(256) void pack_w(const float* __restrict__ w,
                                              f16* __restrict__ bpk) {
    int idx = blockIdx.x * 256 + threadIdx.x;
    if (idx >= NSTEP * 10 * 64) return;
    int l = idx & 63;
    int rest = idx >> 6;
    int f = rest % 10;
    int s = rest / 10;
    int n = f * 16 + (l & 15);
    int k0 = s * 32 + (l >> 4) * 8;
    const float* src = w + (size_t)n * HIDDEN + k0;
    f16x8 hi, lo;
#pragma unroll
    for (int j = 0; j < 8; ++j) {
        float v = src[j];
        f16 hv = (fabsf(v) < F16_MIN_NORM) ? (f16)0.f : (f16)v;
        hi[j] = hv;
        lo[j] = (f16)((v - (float)hv) * 4096.0f);
    }
    f16x8* dst = (f16x8*)bpk;
    dst[idx] = hi;
    dst[BPL + idx] = lo;
}

// ---------- K1: split-f16 MFMA GEMM, partials [KSP][T][160] f32 ----------
// 8 waves = 4 token-frags x 2 expert-halves; wave = 16 tokens x 80 experts
// (acc only 40 regs -> <=128 total -> 16 waves/CU, 2 blocks/CU resident).
// A: x -> hi/lo f16, frag-ordered LDS (linear, conflict-free b128).
// B: bulk-staged to LDS via global_load_lds (20 wave-instrs/block/chunk),
//    stays L2-hot because x loads are nontemporal.
__global__ __launch_bounds__(512, 4) void gemm_mfma(const float* __restrict__ x,
                                                    const f16* __restrict__ bpk,
                                                    float* __restrict__ part, int T) {
    __shared__ __align__(16) f16 Alds[2][512 * 8];    // 8 KB per buf (256 hi + 256 lo units)
    __shared__ __align__(16) f16 Blds[2][1280 * 8];   // 20 KB per buf (640 hi + 640 lo units)

    const int tid  = threadIdx.x;
    const int lane = tid & 63;
    const int wv   = tid >> 6;
    const int bx   = blockIdx.x;
    const int tile = bx >> 1;
    const int ks   = bx & 1;
    const int t0   = tile * BT;
    const int tg   = wv >> 1;          // token frag 0..3
    const int eh   = wv & 1;           // expert half

    // A staging map: thread (tt, qq) owns x[t0+tt][k0 + qq*4 .. +3]
    const int tt = tid >> 3;
    const int qq = tid & 7;
    const float* xrow = x + (size_t)(t0 + tt) * HIDDEN + (size_t)ks * KPB + qq * 4;
    const int au  = (tt >> 4) * 64 + (tt & 15) + 16 * (qq >> 1);  // frag-order unit
    const int ahi = au * 8 + (qq & 1) * 4;
    const int ali = (256 + au) * 8 + (qq & 1) * 4;

    const f16x8* bpk8 = (const f16x8*)bpk;
    const int sg0 = ks * NCH;

    auto stageB = [&](int b, int sg) {
        // units 0..1279 = [hi 0..639 | lo 640..1279], global src contiguous per plane
        int ub = wv * 64;                                  // all waves: units 0..511 (hi)
        {
            int u = ub + lane;
            gl_lds16(bpk8 + (size_t)sg * 640 + u, &Blds[b][(size_t)ub * 8]);
        }
        ub = 512 + wv * 64;                                // waves 0-1: hi tail; 2-7: lo
        {
            int u = ub + lane;
            const f16x8* g = (ub < 640) ? (bpk8 + (size_t)sg * 640 + u)
                                        : (bpk8 + BPL + (size_t)sg * 640 + (u - 640));
            gl_lds16(g, &Blds[b][(size_t)ub * 8]);
        }
        if (wv < 4) {                                      // units 1024..1279 (lo tail)
            ub = 1024 + wv * 64;
            int u = ub + lane;
            gl_lds16(bpk8 + BPL + (size_t)sg * 640 + (u - 640), &Blds[b][(size_t)ub * 8]);
        }
    };

    auto cvtA = [&](int b, f32x4 v) {
        f16x4 hi, lo;
#pragma unroll
        for (int j = 0; j < 4; ++j) {
            float vv = v[j];
            f16 hv = (fabsf(vv) < F16_MIN_NORM) ? (f16)0.f : (f16)vv;
            hi[j] = hv;
            lo[j] = (f16)((vv - (float)hv) * 4096.0f);
        }
        *(f16x4*)&Alds[b][ahi] = hi;
        *(f16x4*)&Alds[b][ali] = lo;
    };

    f32x4 acc0[5], acc1[5];
    const f32x4 z4 = {0.f, 0.f, 0.f, 0.f};
#pragma unroll
    for (int nf = 0; nf < 5; ++nf) { acc0[nf] = z4; acc1[nf] = z4; }

    // prologue: stage chunk 0 into buf 0
    stageB(0, sg0);
    f32x4 xv = __builtin_nontemporal_load((const f32x4*)xrow);
    cvtA(0, xv);
    __syncthreads();

    int buf = 0;
    for (int c = 0; c < NCH; ++c) {
        if (c + 1 < NCH) {
            stageB(buf ^ 1, sg0 + c + 1);
            xv = __builtin_nontemporal_load((const f32x4*)(xrow + (size_t)(c + 1) * KC));
        }
        f16x8 ah = *(const f16x8*)&Alds[buf][(tg * 64 + lane) * 8];
        f16x8 al = *(const f16x8*)&Alds[buf][(256 + tg * 64 + lane) * 8];
#pragma unroll
        for (int nf = 0; nf < 5; ++nf) {
            f16x8 bh = *(const f16x8*)&Blds[buf][((eh * 5 + nf) * 64 + lane) * 8];
            f16x8 bl = *(const f16x8*)&Blds[buf][((640 + (eh * 5 + nf) * 64) + lane) * 8];
            acc0[nf] = __builtin_amdgcn_mfma_f32_16x16x32_f16(ah, bh, acc0[nf], 0, 0, 0);
            acc1[nf] = __builtin_amdgcn_mfma_f32_16x16x32_f16(ah, bl, acc1[nf], 0, 0, 0);
            acc1[nf] = __builtin_amdgcn_mfma_f32_16x16x32_f16(al, bh, acc1[nf], 0, 0, 0);
        }
        if (c + 1 < NCH) cvtA(buf ^ 1, xv);
        __syncthreads();
        buf ^= 1;
    }

    // epilogue: logit = acc0 + acc1/4096; C/D: col=lane&15 (expert), row=h4*4+r (token)
    const int m16 = lane & 15, h4 = lane >> 4;
    const float s12 = 1.0f / 4096.0f;
#pragma unroll
    for (int nf = 0; nf < 5; ++nf) {
        int e  = eh * 80 + nf * 16 + m16;
        int tb = t0 + tg * 16 + h4 * 4;
#pragma unroll
        for (int r = 0; r < 4; ++r)
            part[((size_t)ks * T + tb + r) * NEXP + e] = acc0[nf][r] + acc1[nf][r] * s12;
    }
}

// ---------- K2: 8 lanes per token: combine partials + grouped top-k ----------
// lane g of a token owns group g (20 experts): sum KSP planes, group max,
// local stable top-6; group-select + merge via 8-lane shuffles (no LDS).
__global__ __launch_bounds__(512) void moe_topk3(const float* __restrict__ part,
                                                 float* __restrict__ out, int T) {
    const int tid = threadIdx.x;
    const int tl  = tid >> 3;
    const int g   = tid & 7;
    const int t   = blockIdx.x * 64 + tl;

    const float* r0 = part + (size_t)t * NEXP + g * GSIZE;
    const float* r1 = r0 + (size_t)T * NEXP;

    float v[GSIZE];
    float gmx = -3e38f;
#pragma unroll
    for (int j = 0; j < 5; ++j) {
        f32x4 a = *(const f32x4*)(r0 + j * 4);
        f32x4 b = *(const f32x4*)(r1 + j * 4);
#pragma unroll
        for (int cc = 0; cc < 4; ++cc) {
            float s = a[cc] + b[cc];
            v[j * 4 + cc] = s;
            gmx = fmaxf(gmx, s);
        }
    }

    float gm[NGRP];
#pragma unroll
    for (int i = 0; i < NGRP; ++i) gm[i] = __shfl(gmx, i, 8);

    // top-3 groups, lowest index wins ties (matches stable lax.top_k)
    unsigned gmask = 0;
#pragma unroll
    for (int r = 0; r < TOPKG; ++r) {
        float bv = -3e38f; int bi = 0;
#pragma unroll
        for (int gg = 0; gg < NGRP; ++gg) {
            bool elig = !((gmask >> gg) & 1);
            if (elig && gm[gg] > bv) { bv = gm[gg]; bi = gg; }
        }
        gmask |= 1u << bi;
    }
    const bool sel = (gmask >> g) & 1;

    // local stable top-6 of my group (value desc, index asc)
    float lv[TOPK]; int li[TOPK];
#pragma unroll
    for (int r = 0; r < TOPK; ++r) { lv[r] = -3e38f; li[r] = 1 << 20; }
    if (sel) {
#pragma unroll
        for (int j = 0; j < GSIZE; ++j) {
            float sv = v[j];
            int e = g * GSIZE + j;
            if (sv > lv[TOPK - 1]) {
                lv[TOPK - 1] = sv; li[TOPK - 1] = e;
#pragma unroll
                for (int q = TOPK - 1; q > 0; --q) {
                    if (lv[q] > lv[q - 1]) {
                        float tv = lv[q]; lv[q] = lv[q - 1]; lv[q - 1] = tv;
                        int ti = li[q]; li[q] = li[q - 1]; li[q - 1] = ti;
                    }
                }
            }
        }
    }

    // 8-way merge: each round, butterfly argmax of list heads (tie -> lower e),
    // winner pops its head (static shift; e is unique per lane -> safe identify)
    float vals[TOPK]; int idxs[TOPK];
#pragma unroll
    for (int r = 0; r < TOPK; ++r) {
        float cv = lv[0]; int ce = li[0];
        float bv = cv; int be = ce;
#pragma unroll
        for (int m = 1; m < 8; m <<= 1) {
            float ov = __shfl_xor(bv, m, 8);
            int   oe = __shfl_xor(be, m, 8);
            if (ov > bv || (ov == bv && oe < be)) { bv = ov; be = oe; }
        }
        vals[r] = bv; idxs[r] = be;
        if (be == ce) {
#pragma unroll
            for (int q = 0; q < TOPK - 1; ++q) { lv[q] = lv[q + 1]; li[q] = li[q + 1]; }
            lv[TOPK - 1] = -3e38f; li[TOPK - 1] = 1 << 20;
        }
    }

    if (g == 0) {
        float m0 = vals[0], ssum = 0.f, w6[TOPK];
#pragma unroll
        for (int r = 0; r < TOPK; ++r) { w6[r] = expf(vals[r] - m0); ssum += w6[r]; }
        float inv = 1.f / (ssum + 1e-20f);
#pragma unroll
        for (int r = 0; r < TOPK; ++r) {
            out[(size_t)t * TOPK + r] = (float)idxs[r];
            out[(size_t)T * TOPK + (size_t)t * TOPK + r] = w6[r] * inv;
        }
    }
}

extern "C" void kernel_launch(void* const* d_in, const int* in_sizes, int n_in,
                              void* d_out, int out_size, void* d_ws, size_t ws_size,
                              hipStream_t stream) {
    const float* x = (const float*)d_in[0];
    const float* w = (const float*)d_in[1];
    float* out = (float*)d_out;
    const int T = in_sizes[0] / HIDDEN;  // 16384

    f16* bpk    = (f16*)d_ws;                                  // 3.28 MB (= HIDDEN*NEXP floats)
    float* part = (float*)d_ws + (size_t)HIDDEN * NEXP;        // KSP * T * 160 floats (21 MB)

    pack_w<<<(NSTEP * 10 * 64 + 255) / 256, 256, 0, stream>>>(w, bpk);
    gemm_mfma<<<(T / BT) * KSP, 512, 0, stream>>>(x, bpk, part, T);
    moe_topk3<<<T / 64, 512, 0, stream>>>(part, out, T);
}